// Round 3
// baseline (429.571 us; speedup 1.0000x reference)
//
#include <hip/hip_runtime.h>

typedef __bf16 bf16_t;
typedef __bf16 bf16x8 __attribute__((ext_vector_type(8)));
typedef float f32x4 __attribute__((ext_vector_type(4)));

#define BN_EPS 1e-3f

// ---------------- fp32 -> bf16 elementwise convert (8 elems/thread) ----------------
__global__ __launch_bounds__(256) void cvt_f32_bf16(
    const float* __restrict__ in, bf16_t* __restrict__ out, long n)
{
  long i = ((long)blockIdx.x * 256 + threadIdx.x) * 8;
  if (i + 8 > n) return;
  f32x4 a = *(const f32x4*)(in + i);
  f32x4 b = *(const f32x4*)(in + i + 4);
  bf16x8 o;
  o[0] = (bf16_t)a[0]; o[1] = (bf16_t)a[1]; o[2] = (bf16_t)a[2]; o[3] = (bf16_t)a[3];
  o[4] = (bf16_t)b[0]; o[5] = (bf16_t)b[1]; o[6] = (bf16_t)b[2]; o[7] = (bf16_t)b[3];
  *(bf16x8*)(out + i) = o;
}

// ---------------- weight transpose fp32 in[R][C] -> bf16 out[C][R] ----------------
__global__ __launch_bounds__(256) void transpose_f32_bf16(
    const float* __restrict__ in, bf16_t* __restrict__ out, int R, int C)
{
  __shared__ bf16_t t[32][33];
  int bx = blockIdx.x * 32, by = blockIdx.y * 32;
  int tx = threadIdx.x, ty = threadIdx.y;
#pragma unroll
  for (int i = 0; i < 32; i += 8)
    t[ty + i][tx] = (bf16_t)in[(long)(by + ty + i) * C + (bx + tx)];
  __syncthreads();
#pragma unroll
  for (int i = 0; i < 32; i += 8)
    out[(long)(bx + ty + i) * R + (by + tx)] = t[tx][ty + i];
}

// ---------------- fused GEMM + BN (+ scatter epilogues) ----------------
// MODE 0: KV   A=xb[32768][256], Wt[640][256] -> K[bh][4096][32] (d16..31=0), Vt[bh][64][4096]
// MODE 1: Q    A=xb (strided row gather), Wt[128][256] -> Q[bh][1024][32] (pad 0, *0.25)
// MODE 2: PROJ A=outp[8192][512], Wt[512][512] -> d_out (fp32) [8192][512]
template <int MODE>
__global__ __launch_bounds__(256) void gemm_bn(
    const bf16_t* __restrict__ A, const bf16_t* __restrict__ Wt,
    const float* __restrict__ bias, const float* __restrict__ gamma,
    const float* __restrict__ beta, const float* __restrict__ mean,
    const float* __restrict__ var,
    bf16_t* __restrict__ out0, bf16_t* __restrict__ out1,
    float* __restrict__ outf)
{
  constexpr int KTOT = (MODE == 2) ? 512 : 256;
  const int lane = threadIdx.x & 63;
  const int w = threadIdx.x >> 6;
  const int quad = lane >> 4, l15 = lane & 15;
  const int m0 = blockIdx.x * 64 + w * 16;
  const int n0 = blockIdx.y * 64;

  int mrow = m0 + l15;
  int arow;
  if constexpr (MODE == 1) {
    // q subsample: row -> x row (b, 2*qy, 2*qx)
    int b = mrow >> 10, qp = mrow & 1023;
    arow = (b << 12) + ((qp >> 5) << 7) + ((qp & 31) << 1);
  } else {
    arow = mrow;
  }
  const bf16_t* ap = A + (long)arow * KTOT + quad * 8;
  const bf16_t* bp = Wt + (long)(n0 + l15) * KTOT + quad * 8;

  f32x4 acc[4] = {};
#pragma unroll
  for (int ks = 0; ks < KTOT / 32; ks++) {
    bf16x8 a = *(const bf16x8*)(ap + ks * 32);
#pragma unroll
    for (int nt = 0; nt < 4; nt++) {
      bf16x8 bfr = *(const bf16x8*)(bp + (long)nt * 16 * KTOT + ks * 32);
      acc[nt] = __builtin_amdgcn_mfma_f32_16x16x32_bf16(a, bfr, acc[nt], 0, 0, 0);
    }
  }

#pragma unroll
  for (int nt = 0; nt < 4; nt++) {
    int col = n0 + nt * 16 + l15;
    float s = gamma[col] / sqrtf(var[col] + BN_EPS);
    float t = beta[col] - mean[col] * s;
    float bia = bias[col];
#pragma unroll
    for (int r = 0; r < 4; r++) {
      int grow = m0 + quad * 4 + r;
      float y = (acc[nt][r] + bia) * s + t;
      if constexpr (MODE == 0) {
        int h = col / 80;
        int r80 = col - h * 80;
        int b = grow >> 12, seq = grow & 4095;
        int bh = b * 8 + h;
        if (r80 < 16) {
          long base = ((long)bh * 4096 + seq) * 32;
          out0[base + r80] = (bf16_t)y;          // K [bh][seq][32], d-major
          out0[base + 16 + r80] = (bf16_t)0.f;   // explicit zero pad d 16..31
        } else {
          out1[(long)(bh * 64 + (r80 - 16)) * 4096 + seq] = (bf16_t)y;   // Vt [bh][dv][seq]
        }
      } else if constexpr (MODE == 1) {
        int h = col >> 4, d = col & 15;
        int b = grow >> 10, qp = grow & 1023;
        long qi = ((long)(b * 8 + h) * 1024 + qp) * 32 + d;
        out0[qi] = (bf16_t)(y * 0.25f);   // fold softmax scale KD^-0.5 = 0.25
        out0[qi + 16] = (bf16_t)0.f;      // zero-pad d 16..31 for K=32 MFMA
      } else {
        outf[(long)grow * 512 + col] = y;  // fp32 final output
      }
    }
  }
}

// ---------------- flash attention + hard_swish + TF-faithful scatter ----------------
// grid: 512 blocks = 64 (b,h) x 8 q-blocks of 128. block = 256 thr (4 waves).
// wave handles 2 q-strips of 16 rows. No running max: |S| small; exp arg clamped.
__global__ __launch_bounds__(256) void attn_kernel(
    const bf16_t* __restrict__ Q, const bf16_t* __restrict__ K,
    const bf16_t* __restrict__ Vt, bf16_t* __restrict__ outp)
{
  const int lane = threadIdx.x & 63;
  const int w = threadIdx.x >> 6;
  const int quad = lane >> 4, l15 = lane & 15;
  const int bh = blockIdx.x >> 3, qb = blockIdx.x & 7;
  const int b = bh >> 3, h = bh & 7;
  const bf16_t* Qp = Q + (long)bh * 1024 * 32;
  const bf16_t* Kp = K + (long)bh * 4096 * 32;
  const bf16_t* Vp = Vt + (long)bh * 64 * 4096;

  // P round-trip LDS: [wave][strip][parity][16 rows x stride 56]
  __shared__ __align__(16) bf16_t Plds[4][2][2][16 * 56];

  const int q0 = qb * 128 + w * 32;
  bf16x8 qf[2];
  qf[0] = *(const bf16x8*)(Qp + (q0 + l15) * 32 + quad * 8);
  qf[1] = *(const bf16x8*)(Qp + (q0 + 16 + l15) * 32 + quad * 8);

  f32x4 O[2][4] = {};
  float lp[2][4] = {};
  const f32x4 zf = {0.f, 0.f, 0.f, 0.f};

  for (int kt = 0; kt < 128; kt++) {
    const int kk0 = kt * 32;
    // K fragment: rows padded to 32 with zeros -> fully in-bounds, pad*pad = 0
    bf16x8 kf0 = *(const bf16x8*)(Kp + (long)(kk0 + l15) * 32 + quad * 8);
    bf16x8 kf1 = *(const bf16x8*)(Kp + (long)(kk0 + 16 + l15) * 32 + quad * 8);
    bf16x8 vf[4];
#pragma unroll
    for (int dt = 0; dt < 4; dt++)
      vf[dt] = *(const bf16x8*)(Vp + (long)(dt * 16 + l15) * 4096 + kk0 + quad * 8);

    const int par = kt & 1;
#pragma unroll
    for (int s = 0; s < 2; s++) {
      f32x4 S0 = __builtin_amdgcn_mfma_f32_16x16x32_bf16(qf[s], kf0, zf, 0, 0, 0);
      f32x4 S1 = __builtin_amdgcn_mfma_f32_16x16x32_bf16(qf[s], kf1, zf, 0, 0, 0);
      bf16_t* P = &Plds[w][s][par][0];
#pragma unroll
      for (int r = 0; r < 4; r++) {
        float p0 = __expf(fminf(fmaxf(S0[r], -80.f), 80.f));
        float p1 = __expf(fminf(fmaxf(S1[r], -80.f), 80.f));
        lp[s][r] += p0 + p1;
        P[(quad * 4 + r) * 56 + l15] = (bf16_t)p0;
        P[(quad * 4 + r) * 56 + 16 + l15] = (bf16_t)p1;
      }
    }
    __syncthreads();
#pragma unroll
    for (int s = 0; s < 2; s++) {
      bf16x8 pf = *(const bf16x8*)(&Plds[w][s][par][l15 * 56 + quad * 8]);
#pragma unroll
      for (int dt = 0; dt < 4; dt++)
        O[s][dt] = __builtin_amdgcn_mfma_f32_16x16x32_bf16(pf, vf[dt], O[s][dt], 0, 0, 0);
    }
  }

#pragma unroll
  for (int s = 0; s < 2; s++) {
    float lt[4];
#pragma unroll
    for (int r = 0; r < 4; r++) {
      float v = lp[s][r];
      v += __shfl_xor(v, 1);
      v += __shfl_xor(v, 2);
      v += __shfl_xor(v, 4);
      v += __shfl_xor(v, 8);
      lt[r] = v;
    }
#pragma unroll
    for (int dt = 0; dt < 4; dt++) {
      int dv = dt * 16 + l15;
#pragma unroll
      for (int r = 0; r < 4; r++) {
        int q = q0 + s * 16 + quad * 4 + r;
        float val = O[s][dt][r] / lt[r];
        float hs = val * fminf(fmaxf(val + 3.f, 0.f), 6.f) * (1.f / 6.f);
        // out_pre[b][h*128 + dv*2 + (q>>9)][q&511]  (transpose(0,1,3,2)+reshape)
        long row = (long)h * 128 + dv * 2 + (q >> 9);
        outp[((long)b * 1024 + row) * 512 + (q & 511)] = (bf16_t)hs;
      }
    }
  }
}

extern "C" void kernel_launch(void* const* d_in, const int* in_sizes, int n_in,
                              void* d_out, int out_size, void* d_ws, size_t ws_size,
                              hipStream_t stream)
{
  const float* x    = (const float*)d_in[0];
  const float* Wkv  = (const float*)d_in[1];
  const float* bkv  = (const float*)d_in[2];
  const float* g_kv = (const float*)d_in[3];
  const float* b_kv = (const float*)d_in[4];
  const float* m_kv = (const float*)d_in[5];
  const float* v_kv = (const float*)d_in[6];
  const float* Wq   = (const float*)d_in[7];
  const float* bq   = (const float*)d_in[8];
  const float* g_q  = (const float*)d_in[9];
  const float* b_q  = (const float*)d_in[10];
  const float* m_q  = (const float*)d_in[11];
  const float* v_q  = (const float*)d_in[12];
  const float* Wp   = (const float*)d_in[13];
  const float* bp   = (const float*)d_in[14];
  const float* g_p  = (const float*)d_in[15];
  const float* b_p  = (const float*)d_in[16];
  const float* m_p  = (const float*)d_in[17];
  const float* v_p  = (const float*)d_in[18];

  char* ws = (char*)d_ws;
  bf16_t* xb    = (bf16_t*)ws; ws += (long)8 * 4096 * 256 * 2;
  bf16_t* Wkv_t = (bf16_t*)ws; ws += (long)640 * 256 * 2;
  bf16_t* Wq_t  = (bf16_t*)ws; ws += (long)128 * 256 * 2;
  bf16_t* Wp_t  = (bf16_t*)ws; ws += (long)512 * 512 * 2;
  bf16_t* Qbuf  = (bf16_t*)ws; ws += (long)64 * 1024 * 32 * 2;
  bf16_t* Kbuf  = (bf16_t*)ws; ws += (long)64 * 4096 * 32 * 2;
  bf16_t* Vtb   = (bf16_t*)ws; ws += (long)64 * 64 * 4096 * 2;
  bf16_t* outp  = (bf16_t*)ws; ws += (long)8192 * 512 * 2;

  cvt_f32_bf16<<<dim3(4096), 256, 0, stream>>>(x, xb, (long)8 * 4096 * 256);

  transpose_f32_bf16<<<dim3(20, 8),  dim3(32, 8), 0, stream>>>(Wkv, Wkv_t, 256, 640);
  transpose_f32_bf16<<<dim3(4, 8),   dim3(32, 8), 0, stream>>>(Wq,  Wq_t,  256, 128);
  transpose_f32_bf16<<<dim3(16, 16), dim3(32, 8), 0, stream>>>(Wp,  Wp_t,  512, 512);

  gemm_bn<0><<<dim3(512, 10), 256, 0, stream>>>(xb, Wkv_t, bkv, g_kv, b_kv, m_kv, v_kv, Kbuf, Vtb, nullptr);
  gemm_bn<1><<<dim3(128, 2),  256, 0, stream>>>(xb, Wq_t,  bq,  g_q,  b_q,  m_q,  v_q,  Qbuf, nullptr, nullptr);

  attn_kernel<<<dim3(512), 256, 0, stream>>>(Qbuf, Kbuf, Vtb, outp);

  gemm_bn<2><<<dim3(128, 8), 256, 0, stream>>>(outp, Wp_t, bp, g_p, b_p, m_p, v_p, nullptr, nullptr, (float*)d_out);
}

// Round 4
// 410.268 us; speedup vs baseline: 1.0471x; 1.0471x over previous
//
#include <hip/hip_runtime.h>

typedef __bf16 bf16_t;
typedef __bf16 bf16x8 __attribute__((ext_vector_type(8)));
typedef float f32x4 __attribute__((ext_vector_type(4)));

#define BN_EPS 1e-3f

// ---------------- fp32 -> bf16 elementwise convert (8 elems/thread) ----------------
__global__ __launch_bounds__(256) void cvt_f32_bf16(
    const float* __restrict__ in, bf16_t* __restrict__ out, long n)
{
  long i = ((long)blockIdx.x * 256 + threadIdx.x) * 8;
  if (i + 8 > n) return;
  f32x4 a = *(const f32x4*)(in + i);
  f32x4 b = *(const f32x4*)(in + i + 4);
  bf16x8 o;
  o[0] = (bf16_t)a[0]; o[1] = (bf16_t)a[1]; o[2] = (bf16_t)a[2]; o[3] = (bf16_t)a[3];
  o[4] = (bf16_t)b[0]; o[5] = (bf16_t)b[1]; o[6] = (bf16_t)b[2]; o[7] = (bf16_t)b[3];
  *(bf16x8*)(out + i) = o;
}

// ---------------- weight transpose fp32 in[R][C] -> bf16 out[C][R] ----------------
__global__ __launch_bounds__(256) void transpose_f32_bf16(
    const float* __restrict__ in, bf16_t* __restrict__ out, int R, int C)
{
  __shared__ bf16_t t[32][33];
  int bx = blockIdx.x * 32, by = blockIdx.y * 32;
  int tx = threadIdx.x, ty = threadIdx.y;
#pragma unroll
  for (int i = 0; i < 32; i += 8)
    t[ty + i][tx] = (bf16_t)in[(long)(by + ty + i) * C + (bx + tx)];
  __syncthreads();
#pragma unroll
  for (int i = 0; i < 32; i += 8)
    out[(long)(bx + ty + i) * R + (by + tx)] = t[tx][ty + i];
}

// ---------------- fused GEMM + BN (+ scatter epilogues) ----------------
// MODE 0: KV   A=xb[32768][256], Wt[640][256] -> K[bh][4096][16], Vt[bh][64][4096]
// MODE 1: Q    A=xb (strided row gather), Wt[128][256] -> Q[bh][1024][32] (pad 0, *0.25)
// MODE 2: PROJ A=outp[8192][512], Wt[512][512] -> d_out (fp32) [8192][512]
template <int MODE>
__global__ __launch_bounds__(256) void gemm_bn(
    const bf16_t* __restrict__ A, const bf16_t* __restrict__ Wt,
    const float* __restrict__ bias, const float* __restrict__ gamma,
    const float* __restrict__ beta, const float* __restrict__ mean,
    const float* __restrict__ var,
    bf16_t* __restrict__ out0, bf16_t* __restrict__ out1,
    float* __restrict__ outf)
{
  constexpr int KTOT = (MODE == 2) ? 512 : 256;
  const int lane = threadIdx.x & 63;
  const int w = threadIdx.x >> 6;
  const int quad = lane >> 4, l15 = lane & 15;
  const int m0 = blockIdx.x * 64 + w * 16;
  const int n0 = blockIdx.y * 64;

  int mrow = m0 + l15;
  int arow;
  if constexpr (MODE == 1) {
    int b = mrow >> 10, qp = mrow & 1023;
    arow = (b << 12) + ((qp >> 5) << 7) + ((qp & 31) << 1);
  } else {
    arow = mrow;
  }
  const bf16_t* ap = A + (long)arow * KTOT + quad * 8;
  const bf16_t* bp = Wt + (long)(n0 + l15) * KTOT + quad * 8;

  f32x4 acc[4] = {};
#pragma unroll
  for (int ks = 0; ks < KTOT / 32; ks++) {
    bf16x8 a = *(const bf16x8*)(ap + ks * 32);
#pragma unroll
    for (int nt = 0; nt < 4; nt++) {
      bf16x8 bfr = *(const bf16x8*)(bp + (long)nt * 16 * KTOT + ks * 32);
      acc[nt] = __builtin_amdgcn_mfma_f32_16x16x32_bf16(a, bfr, acc[nt], 0, 0, 0);
    }
  }

#pragma unroll
  for (int nt = 0; nt < 4; nt++) {
    int col = n0 + nt * 16 + l15;
    float s = gamma[col] / sqrtf(var[col] + BN_EPS);
    float t = beta[col] - mean[col] * s;
    float bia = bias[col];
#pragma unroll
    for (int r = 0; r < 4; r++) {
      int grow = m0 + quad * 4 + r;
      float y = (acc[nt][r] + bia) * s + t;
      if constexpr (MODE == 0) {
        int h = col / 80;
        int r80 = col - h * 80;
        int b = grow >> 12, seq = grow & 4095;
        int bh = b * 8 + h;
        if (r80 < 16)
          out0[((long)bh * 4096 + seq) * 16 + r80] = (bf16_t)y;          // K [bh][seq][16]
        else
          out1[(long)(bh * 64 + (r80 - 16)) * 4096 + seq] = (bf16_t)y;   // Vt [bh][dv][seq]
      } else if constexpr (MODE == 1) {
        int h = col >> 4, d = col & 15;
        int b = grow >> 10, qp = grow & 1023;
        long qi = ((long)(b * 8 + h) * 1024 + qp) * 32 + d;
        out0[qi] = (bf16_t)(y * 0.25f);   // fold softmax scale
        out0[qi + 16] = (bf16_t)0.f;      // zero-pad d 16..31 (makes K overread harmless)
      } else {
        outf[(long)grow * 512 + col] = y;
      }
    }
  }
}

// ---------------- flash attention, split-K across wave halves ----------------
// grid 512 = 64 (b,h) x 8 q-blocks of 128. block = 512 thr (8 waves).
// waves 0-3: q-strip w, keys 0..2047; waves 4-7: q-strip w-4, keys 2048..4095.
// Partial (O,l) combine linearly (no online max needed; exp arg clamped).
__global__ __launch_bounds__(512, 4) void attn_kernel(
    const bf16_t* __restrict__ Q, const bf16_t* __restrict__ K,
    const bf16_t* __restrict__ Vt, bf16_t* __restrict__ outp)
{
  const int tid = threadIdx.x;
  const int lane = tid & 63, w = tid >> 6;
  const int quad = lane >> 4, l15 = lane & 15;
  const int ws4 = w & 3, kh = w >> 2;
  const int bh = blockIdx.x >> 3, qb = blockIdx.x & 7;
  const int b = bh >> 3, h = bh & 7;
  const bf16_t* Qp = Q + (long)bh * 1024 * 32;
  const bf16_t* Kp = K + (long)bh * 4096 * 16;
  const bf16_t* Vp = Vt + (long)bh * 64 * 4096;

  // P slices: 8 waves x 2 parity x 2 strips x [16 rows x stride 40] bf16 = 40960 B
  // combine area (aliased after k-loop): 4 waves x 64 lanes x 44 f32 = 45056 B
  __shared__ __align__(16) char smem[45056];
  bf16_t* Pb = (bf16_t*)smem;

  const int q0 = qb * 128 + ws4 * 32;
  bf16x8 qf[2];
  qf[0] = *(const bf16x8*)(Qp + (q0 + l15) * 32 + quad * 8);
  qf[1] = *(const bf16x8*)(Qp + (q0 + 16 + l15) * 32 + quad * 8);

  f32x4 O[2][4] = {};
  float lp[2][4] = {};
  const f32x4 zf = {0.f, 0.f, 0.f, 0.f};

  const int kbeg = kh * 64;           // starting 32-key tile
  // prefetch tile kbeg
  bf16x8 kf0 = *(const bf16x8*)(Kp + (long)(kbeg * 32 + l15) * 16 + quad * 8);
  bf16x8 kf1 = *(const bf16x8*)(Kp + (long)(kbeg * 32 + 16 + l15) * 16 + quad * 8);
  bf16x8 vf[4];
#pragma unroll
  for (int dt = 0; dt < 4; dt++)
    vf[dt] = *(const bf16x8*)(Vp + (long)(dt * 16 + l15) * 4096 + kbeg * 32 + quad * 8);

  for (int kt = 0; kt < 64; kt++) {
    // prefetch next tile (last iter overreads into adjacent ws buffers: in-bounds, unused)
    const int kk0n = (kbeg + kt + 1) * 32;
    bf16x8 nkf0 = *(const bf16x8*)(Kp + (long)(kk0n + l15) * 16 + quad * 8);
    bf16x8 nkf1 = *(const bf16x8*)(Kp + (long)(kk0n + 16 + l15) * 16 + quad * 8);
    bf16x8 nvf[4];
#pragma unroll
    for (int dt = 0; dt < 4; dt++)
      nvf[dt] = *(const bf16x8*)(Vp + (long)(dt * 16 + l15) * 4096 + kk0n + quad * 8);

    const int par = kt & 1;
#pragma unroll
    for (int s = 0; s < 2; s++) {
      f32x4 S0 = __builtin_amdgcn_mfma_f32_16x16x32_bf16(qf[s], kf0, zf, 0, 0, 0);
      f32x4 S1 = __builtin_amdgcn_mfma_f32_16x16x32_bf16(qf[s], kf1, zf, 0, 0, 0);
      bf16_t* P = Pb + (w * 4 + par * 2 + s) * 640;
#pragma unroll
      for (int r = 0; r < 4; r++) {
        float p0 = __expf(fminf(fmaxf(S0[r], -80.f), 80.f));
        float p1 = __expf(fminf(fmaxf(S1[r], -80.f), 80.f));
        lp[s][r] += p0 + p1;
        P[(quad * 4 + r) * 40 + l15] = (bf16_t)p0;
        P[(quad * 4 + r) * 40 + 16 + l15] = (bf16_t)p1;
      }
    }
    // wave-private LDS round-trip: only need this wave's writes visible
    __asm__ volatile("s_waitcnt lgkmcnt(0)" ::: "memory");
#pragma unroll
    for (int s = 0; s < 2; s++) {
      bf16x8 pf = *(const bf16x8*)(Pb + (w * 4 + par * 2 + s) * 640 + l15 * 40 + quad * 8);
#pragma unroll
      for (int dt = 0; dt < 4; dt++)
        O[s][dt] = __builtin_amdgcn_mfma_f32_16x16x32_bf16(pf, vf[dt], O[s][dt], 0, 0, 0);
    }
    kf0 = nkf0; kf1 = nkf1;
#pragma unroll
    for (int dt = 0; dt < 4; dt++) vf[dt] = nvf[dt];
  }

  // ------- combine key-halves -------
  __syncthreads();
  float* comb = (float*)smem;
  if (w >= 4) {
    float* dst = comb + ((w - 4) * 64 + lane) * 44;
#pragma unroll
    for (int s = 0; s < 2; s++)
#pragma unroll
      for (int dt = 0; dt < 4; dt++)
        *(f32x4*)(dst + (s * 4 + dt) * 4) = O[s][dt];
#pragma unroll
    for (int s = 0; s < 2; s++)
#pragma unroll
      for (int r = 0; r < 4; r++)
        dst[32 + s * 4 + r] = lp[s][r];
  }
  __syncthreads();
  if (w < 4) {
    const float* src = comb + (w * 64 + lane) * 44;
#pragma unroll
    for (int s = 0; s < 2; s++)
#pragma unroll
      for (int dt = 0; dt < 4; dt++)
        O[s][dt] += *(const f32x4*)(src + (s * 4 + dt) * 4);
#pragma unroll
    for (int s = 0; s < 2; s++)
#pragma unroll
      for (int r = 0; r < 4; r++)
        lp[s][r] += src[32 + s * 4 + r];

#pragma unroll
    for (int s = 0; s < 2; s++) {
      float lt[4];
#pragma unroll
      for (int r = 0; r < 4; r++) {
        float v = lp[s][r];
        v += __shfl_xor(v, 1);
        v += __shfl_xor(v, 2);
        v += __shfl_xor(v, 4);
        v += __shfl_xor(v, 8);
        lt[r] = v;
      }
#pragma unroll
      for (int dt = 0; dt < 4; dt++) {
        int dv = dt * 16 + l15;
#pragma unroll
        for (int r = 0; r < 4; r++) {
          int q = q0 + s * 16 + quad * 4 + r;
          float val = O[s][dt][r] / lt[r];
          float hs = val * fminf(fmaxf(val + 3.f, 0.f), 6.f) * (1.f / 6.f);
          long row = (long)h * 128 + dv * 2 + (q >> 9);
          outp[((long)b * 1024 + row) * 512 + (q & 511)] = (bf16_t)hs;
        }
      }
    }
  }
}

extern "C" void kernel_launch(void* const* d_in, const int* in_sizes, int n_in,
                              void* d_out, int out_size, void* d_ws, size_t ws_size,
                              hipStream_t stream)
{
  const float* x    = (const float*)d_in[0];
  const float* Wkv  = (const float*)d_in[1];
  const float* bkv  = (const float*)d_in[2];
  const float* g_kv = (const float*)d_in[3];
  const float* b_kv = (const float*)d_in[4];
  const float* m_kv = (const float*)d_in[5];
  const float* v_kv = (const float*)d_in[6];
  const float* Wq   = (const float*)d_in[7];
  const float* bq   = (const float*)d_in[8];
  const float* g_q  = (const float*)d_in[9];
  const float* b_q  = (const float*)d_in[10];
  const float* m_q  = (const float*)d_in[11];
  const float* v_q  = (const float*)d_in[12];
  const float* Wp   = (const float*)d_in[13];
  const float* bp   = (const float*)d_in[14];
  const float* g_p  = (const float*)d_in[15];
  const float* b_p  = (const float*)d_in[16];
  const float* m_p  = (const float*)d_in[17];
  const float* v_p  = (const float*)d_in[18];

  char* ws = (char*)d_ws;
  bf16_t* xb    = (bf16_t*)ws; ws += (long)8 * 4096 * 256 * 2;
  bf16_t* Wkv_t = (bf16_t*)ws; ws += (long)640 * 256 * 2;
  bf16_t* Wq_t  = (bf16_t*)ws; ws += (long)128 * 256 * 2;
  bf16_t* Wp_t  = (bf16_t*)ws; ws += (long)512 * 512 * 2;
  bf16_t* Qbuf  = (bf16_t*)ws; ws += (long)64 * 1024 * 32 * 2;
  bf16_t* Kbuf  = (bf16_t*)ws; ws += (long)64 * 4096 * 16 * 2;
  bf16_t* Vtb   = (bf16_t*)ws; ws += (long)64 * 64 * 4096 * 2;
  bf16_t* outp  = (bf16_t*)ws; ws += (long)8192 * 512 * 2;

  cvt_f32_bf16<<<dim3(4096), 256, 0, stream>>>(x, xb, (long)8 * 4096 * 256);

  transpose_f32_bf16<<<dim3(20, 8),  dim3(32, 8), 0, stream>>>(Wkv, Wkv_t, 256, 640);
  transpose_f32_bf16<<<dim3(4, 8),   dim3(32, 8), 0, stream>>>(Wq,  Wq_t,  256, 128);
  transpose_f32_bf16<<<dim3(16, 16), dim3(32, 8), 0, stream>>>(Wp,  Wp_t,  512, 512);

  gemm_bn<0><<<dim3(512, 10), 256, 0, stream>>>(xb, Wkv_t, bkv, g_kv, b_kv, m_kv, v_kv, Kbuf, Vtb, nullptr);
  gemm_bn<1><<<dim3(128, 2),  256, 0, stream>>>(xb, Wq_t,  bq,  g_q,  b_q,  m_q,  v_q,  Qbuf, nullptr, nullptr);

  attn_kernel<<<dim3(512), 512, 0, stream>>>(Qbuf, Kbuf, Vtb, outp);

  gemm_bn<2><<<dim3(128, 8), 256, 0, stream>>>(outp, Wp_t, bp, g_p, b_p, m_p, v_p, nullptr, nullptr, (float*)d_out);
}

// Round 5
// 407.591 us; speedup vs baseline: 1.0539x; 1.0066x over previous
//
#include <hip/hip_runtime.h>

typedef __bf16 bf16_t;
typedef __bf16 bf16x8 __attribute__((ext_vector_type(8)));
typedef float f32x4 __attribute__((ext_vector_type(4)));

#define BN_EPS 1e-3f

// ---------------- fp32 -> bf16 elementwise convert (8 elems/thread) ----------------
__global__ __launch_bounds__(256) void cvt_f32_bf16(
    const float* __restrict__ in, bf16_t* __restrict__ out, long n)
{
  long i = ((long)blockIdx.x * 256 + threadIdx.x) * 8;
  if (i + 8 > n) return;
  f32x4 a = *(const f32x4*)(in + i);
  f32x4 b = *(const f32x4*)(in + i + 4);
  bf16x8 o;
  o[0] = (bf16_t)a[0]; o[1] = (bf16_t)a[1]; o[2] = (bf16_t)a[2]; o[3] = (bf16_t)a[3];
  o[4] = (bf16_t)b[0]; o[5] = (bf16_t)b[1]; o[6] = (bf16_t)b[2]; o[7] = (bf16_t)b[3];
  *(bf16x8*)(out + i) = o;
}

// ---------------- weight transpose fp32 in[R][C] -> bf16 out[C][R] ----------------
__global__ __launch_bounds__(256) void transpose_f32_bf16(
    const float* __restrict__ in, bf16_t* __restrict__ out, int R, int C)
{
  __shared__ bf16_t t[32][33];
  int bx = blockIdx.x * 32, by = blockIdx.y * 32;
  int tx = threadIdx.x, ty = threadIdx.y;
#pragma unroll
  for (int i = 0; i < 32; i += 8)
    t[ty + i][tx] = (bf16_t)in[(long)(by + ty + i) * C + (bx + tx)];
  __syncthreads();
#pragma unroll
  for (int i = 0; i < 32; i += 8)
    out[(long)(bx + ty + i) * R + (by + tx)] = t[tx][ty + i];
}

// ---------------- fused GEMM + BN (+ scatter epilogues) ----------------
// MODE 0: KV   A=xb[32768][256], Wt[640][256] -> K[bh][4096][16], Vt[bh][64][4096]
// MODE 1: Q    A=xb (strided row gather), Wt[128][256] -> Q[bh][1024][32] (pad 0, *0.25*log2e)
// MODE 2: PROJ A=outp[8192][512], Wt[512][512] -> d_out (fp32) [8192][512]
template <int MODE>
__global__ __launch_bounds__(256) void gemm_bn(
    const bf16_t* __restrict__ A, const bf16_t* __restrict__ Wt,
    const float* __restrict__ bias, const float* __restrict__ gamma,
    const float* __restrict__ beta, const float* __restrict__ mean,
    const float* __restrict__ var,
    bf16_t* __restrict__ out0, bf16_t* __restrict__ out1,
    float* __restrict__ outf)
{
  constexpr int KTOT = (MODE == 2) ? 512 : 256;
  const int lane = threadIdx.x & 63;
  const int w = threadIdx.x >> 6;
  const int quad = lane >> 4, l15 = lane & 15;
  const int m0 = blockIdx.x * 64 + w * 16;
  const int n0 = blockIdx.y * 64;

  int mrow = m0 + l15;
  int arow;
  if constexpr (MODE == 1) {
    int b = mrow >> 10, qp = mrow & 1023;
    arow = (b << 12) + ((qp >> 5) << 7) + ((qp & 31) << 1);
  } else {
    arow = mrow;
  }
  const bf16_t* ap = A + (long)arow * KTOT + quad * 8;
  const bf16_t* bp = Wt + (long)(n0 + l15) * KTOT + quad * 8;

  f32x4 acc[4] = {};
#pragma unroll
  for (int ks = 0; ks < KTOT / 32; ks++) {
    bf16x8 a = *(const bf16x8*)(ap + ks * 32);
#pragma unroll
    for (int nt = 0; nt < 4; nt++) {
      bf16x8 bfr = *(const bf16x8*)(bp + (long)nt * 16 * KTOT + ks * 32);
      acc[nt] = __builtin_amdgcn_mfma_f32_16x16x32_bf16(a, bfr, acc[nt], 0, 0, 0);
    }
  }

#pragma unroll
  for (int nt = 0; nt < 4; nt++) {
    int col = n0 + nt * 16 + l15;
    float s = gamma[col] / sqrtf(var[col] + BN_EPS);
    float t = beta[col] - mean[col] * s;
    float bia = bias[col];
#pragma unroll
    for (int r = 0; r < 4; r++) {
      int grow = m0 + quad * 4 + r;
      float y = (acc[nt][r] + bia) * s + t;
      if constexpr (MODE == 0) {
        int h = col / 80;
        int r80 = col - h * 80;
        int b = grow >> 12, seq = grow & 4095;
        int bh = b * 8 + h;
        if (r80 < 16)
          out0[((long)bh * 4096 + seq) * 16 + r80] = (bf16_t)y;          // K [bh][seq][16]
        else
          out1[(long)(bh * 64 + (r80 - 16)) * 4096 + seq] = (bf16_t)y;   // Vt [bh][dv][seq]
      } else if constexpr (MODE == 1) {
        int h = col >> 4, d = col & 15;
        int b = grow >> 10, qp = grow & 1023;
        long qi = ((long)(b * 8 + h) * 1024 + qp) * 32 + d;
        out0[qi] = (bf16_t)(y * 0.36067376f);  // 0.25 (kd^-.5) * log2(e), for exp2 softmax
        out0[qi + 16] = (bf16_t)0.f;           // zero-pad d 16..31 (makes K overread harmless)
      } else {
        outf[(long)grow * 512 + col] = y;
      }
    }
  }
}

// ---------------- flash attention, copy-free 2-deep pipeline ----------------
// grid 1024 = 64 (b,h) x 16 q-blocks of 64. block = 256 thr (4 waves).
// wave w: qg=w&1 (2 strips of 16 q rows), kh=w>>1 (keys kh*2048..+2048).
// Partial (O,l) combine linearly; softmax via exp2 (log2e folded into Q).
__global__ __launch_bounds__(256, 3) void attn_kernel(
    const bf16_t* __restrict__ Q, const bf16_t* __restrict__ K,
    const bf16_t* __restrict__ Vt, bf16_t* __restrict__ outp)
{
  const int tid = threadIdx.x;
  const int lane = tid & 63, w = tid >> 6;
  const int quad = lane >> 4, l15 = lane & 15;
  const int qg = w & 1, kh = w >> 1;
  const int bh = blockIdx.x >> 4, qb = blockIdx.x & 15;
  const int b = bh >> 3, h = bh & 7;
  const bf16_t* Qp = Q + (long)bh * 1024 * 32;
  const bf16_t* Kp = K + (long)bh * 4096 * 16;
  const bf16_t* Vp = Vt + (long)bh * 64 * 4096;

  // P slices: 4 waves x 2 strips x [16 rows x stride 40] bf16 = 10240 B
  // combine area (aliased after k-loop): 2 qg x 64 lanes x 40 f32 = 20480 B
  __shared__ __align__(16) char smem[20480];
  bf16_t* Pb = (bf16_t*)smem;
  bf16_t* Pw0 = Pb + (w * 2 + 0) * 640;
  bf16_t* Pw1 = Pb + (w * 2 + 1) * 640;

  const int q0 = qb * 64 + qg * 32;
  bf16x8 qf[2];
  qf[0] = *(const bf16x8*)(Qp + (long)(q0 + l15) * 32 + quad * 8);
  qf[1] = *(const bf16x8*)(Qp + (long)(q0 + 16 + l15) * 32 + quad * 8);

  f32x4 O[2][4] = {};
  float lp[2][4] = {};
  const f32x4 zf = {0.f, 0.f, 0.f, 0.f};

  const long kstart = (long)kh * 2048;
  const bf16_t* kp = Kp + (kstart + l15) * 16 + quad * 8;        // + t*512 per 32-key tile
  const bf16_t* vp = Vp + (long)l15 * 4096 + kstart + quad * 8;  // + dt*65536 + t*32

  auto loadK = [&](int t, bf16x8& k0, bf16x8& k1) {
    k0 = *(const bf16x8*)(kp + (long)t * 512);
    k1 = *(const bf16x8*)(kp + (long)t * 512 + 256);
  };
  auto loadV = [&](int t, bf16x8* v) {
#pragma unroll
    for (int dt = 0; dt < 4; dt++)
      v[dt] = *(const bf16x8*)(vp + (long)dt * 65536 + t * 32);
  };
  auto compute = [&](bf16x8 kf0, bf16x8 kf1, const bf16x8* vf) {
#pragma unroll
    for (int s = 0; s < 2; s++) {
      f32x4 S0 = __builtin_amdgcn_mfma_f32_16x16x32_bf16(qf[s], kf0, zf, 0, 0, 0);
      f32x4 S1 = __builtin_amdgcn_mfma_f32_16x16x32_bf16(qf[s], kf1, zf, 0, 0, 0);
      bf16_t* P = s ? Pw1 : Pw0;
#pragma unroll
      for (int r = 0; r < 4; r++) {
        float p0 = exp2f(S0[r]);          // single v_exp_f32; scale pre-folded into Q
        float p1 = exp2f(S1[r]);
        lp[s][r] += p0 + p1;
        P[(quad * 4 + r) * 40 + l15] = (bf16_t)p0;
        P[(quad * 4 + r) * 40 + 16 + l15] = (bf16_t)p1;
      }
    }
    // wave-private LDS round-trip; DS ops are in-order per wave (no parity buffer needed)
    __asm__ volatile("s_waitcnt lgkmcnt(0)" ::: "memory");
#pragma unroll
    for (int s = 0; s < 2; s++) {
      bf16x8 pf = *(const bf16x8*)((s ? Pw1 : Pw0) + l15 * 40 + quad * 8);
#pragma unroll
      for (int dt = 0; dt < 4; dt++)
        O[s][dt] = __builtin_amdgcn_mfma_f32_16x16x32_bf16(pf, vf[dt], O[s][dt], 0, 0, 0);
    }
  };

  // 2-deep copy-free pipeline over 64 tiles of 32 keys.
  // Tail loads (t=64,65) overread into adjacent workspace buffers: in-bounds, unused.
  bf16x8 ak0, ak1, bk0, bk1, av[4], bv[4];
  loadK(0, ak0, ak1); loadV(0, av);
  loadK(1, bk0, bk1); loadV(1, bv);
  for (int kt = 0; kt < 64; kt += 2) {
    compute(ak0, ak1, av);
    loadK(kt + 2, ak0, ak1); loadV(kt + 2, av);
    compute(bk0, bk1, bv);
    loadK(kt + 3, bk0, bk1); loadV(kt + 3, bv);
  }

  // ------- combine key-halves -------
  __syncthreads();
  float* comb = (float*)smem;
  if (kh == 1) {
    float* dst = comb + ((qg * 64) + lane) * 40;
#pragma unroll
    for (int s = 0; s < 2; s++)
#pragma unroll
      for (int dt = 0; dt < 4; dt++)
        *(f32x4*)(dst + (s * 4 + dt) * 4) = O[s][dt];
#pragma unroll
    for (int s = 0; s < 2; s++)
#pragma unroll
      for (int r = 0; r < 4; r++)
        dst[32 + s * 4 + r] = lp[s][r];
  }
  __syncthreads();
  if (kh == 0) {
    const float* src = comb + ((qg * 64) + lane) * 40;
#pragma unroll
    for (int s = 0; s < 2; s++)
#pragma unroll
      for (int dt = 0; dt < 4; dt++)
        O[s][dt] += *(const f32x4*)(src + (s * 4 + dt) * 4);
#pragma unroll
    for (int s = 0; s < 2; s++)
#pragma unroll
      for (int r = 0; r < 4; r++)
        lp[s][r] += src[32 + s * 4 + r];

#pragma unroll
    for (int s = 0; s < 2; s++) {
      float lt[4];
#pragma unroll
      for (int r = 0; r < 4; r++) {
        float v = lp[s][r];
        v += __shfl_xor(v, 1);
        v += __shfl_xor(v, 2);
        v += __shfl_xor(v, 4);
        v += __shfl_xor(v, 8);
        lt[r] = v;
      }
#pragma unroll
      for (int dt = 0; dt < 4; dt++) {
        int dv = dt * 16 + l15;
#pragma unroll
        for (int r = 0; r < 4; r++) {
          int q = q0 + s * 16 + quad * 4 + r;
          float val = O[s][dt][r] / lt[r];
          float hs = val * fminf(fmaxf(val + 3.f, 0.f), 6.f) * (1.f / 6.f);
          long row = (long)h * 128 + dv * 2 + (q >> 9);
          outp[((long)b * 1024 + row) * 512 + (q & 511)] = (bf16_t)hs;
        }
      }
    }
  }
}

extern "C" void kernel_launch(void* const* d_in, const int* in_sizes, int n_in,
                              void* d_out, int out_size, void* d_ws, size_t ws_size,
                              hipStream_t stream)
{
  const float* x    = (const float*)d_in[0];
  const float* Wkv  = (const float*)d_in[1];
  const float* bkv  = (const float*)d_in[2];
  const float* g_kv = (const float*)d_in[3];
  const float* b_kv = (const float*)d_in[4];
  const float* m_kv = (const float*)d_in[5];
  const float* v_kv = (const float*)d_in[6];
  const float* Wq   = (const float*)d_in[7];
  const float* bq   = (const float*)d_in[8];
  const float* g_q  = (const float*)d_in[9];
  const float* b_q  = (const float*)d_in[10];
  const float* m_q  = (const float*)d_in[11];
  const float* v_q  = (const float*)d_in[12];
  const float* Wp   = (const float*)d_in[13];
  const float* bp   = (const float*)d_in[14];
  const float* g_p  = (const float*)d_in[15];
  const float* b_p  = (const float*)d_in[16];
  const float* m_p  = (const float*)d_in[17];
  const float* v_p  = (const float*)d_in[18];

  char* ws = (char*)d_ws;
  bf16_t* xb    = (bf16_t*)ws; ws += (long)8 * 4096 * 256 * 2;
  bf16_t* Wkv_t = (bf16_t*)ws; ws += (long)640 * 256 * 2;
  bf16_t* Wq_t  = (bf16_t*)ws; ws += (long)128 * 256 * 2;
  bf16_t* Wp_t  = (bf16_t*)ws; ws += (long)512 * 512 * 2;
  bf16_t* Qbuf  = (bf16_t*)ws; ws += (long)64 * 1024 * 32 * 2;
  bf16_t* Kbuf  = (bf16_t*)ws; ws += (long)64 * 4096 * 16 * 2;
  bf16_t* Vtb   = (bf16_t*)ws; ws += (long)64 * 64 * 4096 * 2;
  bf16_t* outp  = (bf16_t*)ws; ws += (long)8192 * 512 * 2;

  cvt_f32_bf16<<<dim3(4096), 256, 0, stream>>>(x, xb, (long)8 * 4096 * 256);

  transpose_f32_bf16<<<dim3(20, 8),  dim3(32, 8), 0, stream>>>(Wkv, Wkv_t, 256, 640);
  transpose_f32_bf16<<<dim3(4, 8),   dim3(32, 8), 0, stream>>>(Wq,  Wq_t,  256, 128);
  transpose_f32_bf16<<<dim3(16, 16), dim3(32, 8), 0, stream>>>(Wp,  Wp_t,  512, 512);

  gemm_bn<0><<<dim3(512, 10), 256, 0, stream>>>(xb, Wkv_t, bkv, g_kv, b_kv, m_kv, v_kv, Kbuf, Vtb, nullptr);
  gemm_bn<1><<<dim3(128, 2),  256, 0, stream>>>(xb, Wq_t,  bq,  g_q,  b_q,  m_q,  v_q,  Qbuf, nullptr, nullptr);

  attn_kernel<<<dim3(1024), 256, 0, stream>>>(Qbuf, Kbuf, Vtb, outp);

  gemm_bn<2><<<dim3(128, 8), 256, 0, stream>>>(outp, Wp_t, bp, g_p, b_p, m_p, v_p, nullptr, nullptr, (float*)d_out);
}